// Round 1
// baseline (417.235 us; speedup 1.0000x reference)
//
#include <hip/hip_runtime.h>
#include <hip/hip_bf16.h>
#include <stdint.h>

// ---------------------------------------------------------------------------
// RegionLayer: 64 regions (8x8 grid of 8x8 patches), per-region:
//   hh = relu(BN(x));  y = conv3x3(hh, w[net]) + b[net] + x
// net = gj*(gi+1).  B=16, C=256, H=W=64, fp32 in/out; conv via bf16 MFMA.
// d_ws layout: [0, 75497472) bf16 weights [net][tap][co][ci]
//              [75497472, +33554432) bf16 hh [reg][b][px][c]
// ---------------------------------------------------------------------------

typedef __attribute__((ext_vector_type(8))) short bf16x8;
typedef __attribute__((ext_vector_type(4))) float f32x4;

typedef const __attribute__((address_space(1))) unsigned int gu32;
typedef __attribute__((address_space(3))) unsigned int lu32;

__device__ __forceinline__ void g2l16(const void* g, void* l) {
  __builtin_amdgcn_global_load_lds((gu32*)g, (lu32*)l, 16, 0, 0);
}

// ---------------------------------------------------------------------------
// Kernel 1: conv_w [net][co][ci][ky][kx] fp32  ->  wb [net][tap][co][ci] bf16
// grid (256, 64) blocks x 256 threads. Reads: each thread 9 contiguous floats
// (wave = 2304B contiguous). Writes: per tap, 64 lanes x 2B contiguous.
// ---------------------------------------------------------------------------
__global__ void wtrans_kernel(const float* __restrict__ w,
                              __hip_bfloat16* __restrict__ wb) {
  const int co  = blockIdx.x;   // 0..255
  const int net = blockIdx.y;   // 0..63
  const int ci  = threadIdx.x;  // 0..255
  const float* src = w + (size_t)((net * 256 + co) * 256 + ci) * 9;
#pragma unroll
  for (int t = 0; t < 9; ++t) {
    wb[(size_t)((net * 9 + t) * 256 + co) * 256 + ci] = __float2bfloat16(src[t]);
  }
}

// ---------------------------------------------------------------------------
// Kernel 2: BN+ReLU + NCHW -> per-region NHWC bf16.
// grid 1024 = (reg, b); 256 threads; LDS transpose tile 64px x 64c (pad +1).
// ---------------------------------------------------------------------------
__global__ void bnrelu_kernel(const float* __restrict__ x,
                              const float* __restrict__ gamma,
                              const float* __restrict__ beta,
                              const float* __restrict__ mean,
                              const float* __restrict__ var,
                              __hip_bfloat16* __restrict__ hh) {
  const int blk = blockIdx.x;
  const int reg = blk >> 4, b = blk & 15;
  const int gi = reg >> 3, gj = reg & 7;
  const int net = gj * (gi + 1);
  const int tid = threadIdx.x;

  __shared__ float sc[256], sh[256];
  __shared__ float tile[64 * 65];

  {
    float g = gamma[net * 256 + tid];
    float bt = beta[net * 256 + tid];
    float m = mean[net * 256 + tid];
    float v = var[net * 256 + tid];
    float s = g * rsqrtf(v + 1e-5f);
    sc[tid] = s;
    sh[tid] = bt - m * s;
  }
  __syncthreads();

  const float* xb = x + (size_t)b * 256 * 4096 + (gi * 8) * 64 + gj * 8;
  __hip_bfloat16* hb = hh + (size_t)(reg * 16 + b) * 64 * 256;

  const int px = tid & 63, cl0 = tid >> 6;      // read mapping
  const int yy = px >> 3, xx = px & 7;
  const int wcl = tid & 63, wpx0 = tid >> 6;    // write mapping

  for (int cc = 0; cc < 4; ++cc) {
    const int c0 = cc * 64;
#pragma unroll
    for (int i = 0; i < 16; ++i) {
      int cl = cl0 + i * 4;
      int c = c0 + cl;
      float v = xb[(size_t)c * 4096 + yy * 64 + xx];
      float h = v * sc[c] + sh[c];
      tile[px * 65 + cl] = fmaxf(h, 0.f);
    }
    __syncthreads();
#pragma unroll
    for (int i = 0; i < 16; ++i) {
      int p = wpx0 + i * 4;
      hb[p * 256 + c0 + wcl] = __float2bfloat16(tile[p * 65 + wcl]);
    }
    __syncthreads();
  }
}

// ---------------------------------------------------------------------------
// Kernel 3: implicit-GEMM conv via mfma_f32_16x16x32_bf16.
// Block = (region r, m-tile mt: batches 2mt..2mt+1 -> M rows 0..127,
//          n-tile nt: out channels nt*128..+127). 256 threads = 4 waves 2x2,
// each wave 64m x 64n (4x4 frags). K loop: 4 c-chunks x 9 taps x (kk=2).
// A/B 16KB tiles staged with global_load_lds(16B) using XOR swizzle
// slot_phys = (slot_log + row&7)&7  -> conflict-free ds_read_b128.
// Tap shift handled at A ds_read (shifted row + cndmask zero at patch edge).
// ---------------------------------------------------------------------------
__global__ __launch_bounds__(256, 2) void conv_kernel(
    const __hip_bfloat16* __restrict__ hh,
    const __hip_bfloat16* __restrict__ wb,
    const float* __restrict__ xin,
    const float* __restrict__ cbias,
    float* __restrict__ outp) {
  __shared__ __align__(16) char sA[16384];
  __shared__ __align__(16) char sB[16384];

  const int bx = blockIdx.x;
  const int r = bx >> 4;
  const int mt = bx & 7;
  const int nt = (bx >> 3) & 1;
  const int gi = r >> 3, gj = r & 7;
  const int net = gj * (gi + 1);

  const int tid = threadIdx.x;
  const int lane = tid & 63;
  const int wv = tid >> 6;
  const int wm = (wv & 1) * 64;
  const int wn = (wv >> 1) * 64;
  const int ln = lane & 15;
  const int q = lane >> 4;

  const __hip_bfloat16* Aslab = hh + (size_t)(r * 16 + mt * 2) * (64 * 256);
  const __hip_bfloat16* Bbase =
      wb + (size_t)(net * 9) * (256 * 256) + (size_t)(nt * 128) * 256;

  // per-lane decode of the 4 A-fragment rows (output pixels)
  int bl[4], py[4], pxr[4];
#pragma unroll
  for (int mf = 0; mf < 4; ++mf) {
    int m = wm + mf * 16 + ln;
    bl[mf] = m >> 6;
    py[mf] = (m >> 3) & 7;
    pxr[mf] = m & 7;
  }
  // B fragment LDS byte offsets (constant across whole K loop)
  int boff[4][2];
#pragma unroll
  for (int nf = 0; nf < 4; ++nf) {
    int nrow = wn + nf * 16 + ln;
#pragma unroll
    for (int kk = 0; kk < 2; ++kk) {
      int sl = kk * 4 + q;
      int sp = (sl + (nrow & 7)) & 7;
      boff[nf][kk] = nrow * 128 + sp * 16;
    }
  }

  f32x4 acc[4][4];
#pragma unroll
  for (int mf = 0; mf < 4; ++mf)
#pragma unroll
    for (int nf = 0; nf < 4; ++nf)
      acc[mf][nf] = (f32x4){0.f, 0.f, 0.f, 0.f};

  const bf16x8 zero8 = {0, 0, 0, 0, 0, 0, 0, 0};

#pragma unroll 1
  for (int cc = 0; cc < 4; ++cc) {
    const int c0 = cc * 64;
    // stage A: 128 rows x 64ch bf16 = 16KB, swizzled source addressing
#pragma unroll
    for (int i = 0; i < 4; ++i) {
      int slot = i * 256 + tid;
      int row = slot >> 3, sp = slot & 7;
      int sl = (sp - (row & 7)) & 7;
      g2l16(Aslab + (size_t)row * 256 + c0 + sl * 8, sA + slot * 16);
    }
#pragma unroll
    for (int tap = 0; tap < 9; ++tap) {
      const int dy = tap / 3 - 1, dx = tap % 3 - 1;
      const __hip_bfloat16* Btap = Bbase + (size_t)tap * (256 * 256);
#pragma unroll
      for (int i = 0; i < 4; ++i) {
        int slot = i * 256 + tid;
        int row = slot >> 3, sp = slot & 7;
        int sl = (sp - (row & 7)) & 7;
        g2l16(Btap + (size_t)row * 256 + c0 + sl * 8, sB + slot * 16);
      }
      __syncthreads();  // drains vmcnt: A+B staging visible

      int arow[4], avalid[4];
#pragma unroll
      for (int mf = 0; mf < 4; ++mf) {
        int sy = py[mf] + dy, sx = pxr[mf] + dx;
        int v = ((unsigned)sy < 8u) & ((unsigned)sx < 8u);
        avalid[mf] = v;
        arow[mf] = (bl[mf] << 6) + (v ? (sy * 8 + sx) : 0);
      }
#pragma unroll
      for (int kk = 0; kk < 2; ++kk) {
        bf16x8 afr[4], bfr[4];
#pragma unroll
        for (int mf = 0; mf < 4; ++mf) {
          int row = arow[mf];
          int sp = ((kk * 4 + q) + (row & 7)) & 7;
          bf16x8 v = *(const bf16x8*)(sA + row * 128 + sp * 16);
          afr[mf] = avalid[mf] ? v : zero8;
        }
#pragma unroll
        for (int nf = 0; nf < 4; ++nf)
          bfr[nf] = *(const bf16x8*)(sB + boff[nf][kk]);
#pragma unroll
        for (int mf = 0; mf < 4; ++mf)
#pragma unroll
          for (int nf = 0; nf < 4; ++nf)
            acc[mf][nf] = __builtin_amdgcn_mfma_f32_16x16x32_bf16(
                afr[mf], bfr[nf], acc[mf][nf], 0, 0, 0);
      }
      __syncthreads();  // compute reads done; safe to overwrite LDS
    }
  }

  // Epilogue: D col = lane&15 (n), row = q*4+reg (m). Each lane's 4 regs are
  // 4 consecutive x-pixels -> aligned float4 residual load + store.
  const int nbase = nt * 128 + wn;
#pragma unroll
  for (int nf = 0; nf < 4; ++nf) {
    const int n = nbase + nf * 16 + ln;
    const float cb = cbias[net * 256 + n];
#pragma unroll
    for (int mf = 0; mf < 4; ++mf) {
      int mloc = wm + mf * 16 + q * 4;
      int b = mt * 2 + (mloc >> 6);
      int px = mloc & 63;
      int yy = px >> 3, x0 = px & 7;
      size_t off =
          (((size_t)b * 256 + n) * 64 + (gi * 8 + yy)) * 64 + (gj * 8 + x0);
      f32x4 res = *(const f32x4*)(xin + off);
      f32x4 o = acc[mf][nf];
      o = o + res;
      o = o + cb;
      *(f32x4*)(outp + off) = o;
    }
  }
}

// ---------------------------------------------------------------------------
extern "C" void kernel_launch(void* const* d_in, const int* in_sizes, int n_in,
                              void* d_out, int out_size, void* d_ws,
                              size_t ws_size, hipStream_t stream) {
  const float* x      = (const float*)d_in[0];
  const float* gamma  = (const float*)d_in[1];
  const float* beta   = (const float*)d_in[2];
  const float* mean   = (const float*)d_in[3];
  const float* var    = (const float*)d_in[4];
  const float* conv_w = (const float*)d_in[5];
  const float* conv_b = (const float*)d_in[6];
  float* out = (float*)d_out;

  __hip_bfloat16* wb = (__hip_bfloat16*)d_ws;                       // 75497472 B
  __hip_bfloat16* hh = (__hip_bfloat16*)((char*)d_ws + 75497472);   // 33554432 B

  wtrans_kernel<<<dim3(256, 64), 256, 0, stream>>>(conv_w, wb);
  bnrelu_kernel<<<1024, 256, 0, stream>>>(x, gamma, beta, mean, var, hh);
  conv_kernel<<<1024, 256, 0, stream>>>(hh, wb, x, conv_b, out);
}